// Round 2
// baseline (348.489 us; speedup 1.0000x reference)
//
#include <hip/hip_runtime.h>
#include <math.h>

#define E   2048
#define H   16
#define DH  128
#define L   8192
#define L1  8193
#define NC  129            // ceil(8193 / 64) key-chunks per head
#define PSTR 132           // partial stride: 128 acc + m + s + pad

// ws float offsets
#define WS_Q      0
#define WS_KI     2048
#define WS_VI     4096
#define WS_VAL    6144
#define WS_PART   8192     // 16 * 129 * 132 floats ≈ 1.1 MB

__global__ __launch_bounds__(256) void init_kernel(const float* __restrict__ bq,
                                                   const float* __restrict__ bk,
                                                   const float* __restrict__ bv,
                                                   const float* __restrict__ bo,
                                                   float* __restrict__ ws,
                                                   float* __restrict__ out) {
    int j = blockIdx.x * 256 + threadIdx.x;
    if (j < E) {
        ws[WS_Q  + j] = bq[j];
        ws[WS_KI + j] = bk[j];
        ws[WS_VI + j] = bv[j];
        out[j] = bo[j];
    }
}

// q/k_i/v_i projections, float4 loads. blocks = 3 mats x 2 j-blocks(1024) x 32 k-chunks(64 rows).
__global__ __launch_bounds__(256) void proj_kernel(const float* __restrict__ x,
                                                   const float* __restrict__ Wq,
                                                   const float* __restrict__ Wk,
                                                   const float* __restrict__ Wv,
                                                   float* __restrict__ ws) {
    int b = blockIdx.x;
    int m = b >> 6;                 // 0..2
    int r = b & 63;
    int jb = r >> 5, kc = r & 31;
    const float* W = (m == 0) ? Wq : (m == 1) ? Wk : Wv;
    float* dst = ws + ((m == 0) ? WS_Q : (m == 1) ? WS_KI : WS_VI);

    __shared__ float xs[64];
    int t = threadIdx.x;
    if (t < 64) xs[t] = x[kc * 64 + t];
    __syncthreads();

    int j = jb * 1024 + t * 4;
    const float* Wp = W + (size_t)(kc * 64) * E + j;
    float4 a = make_float4(0.f, 0.f, 0.f, 0.f);
#pragma unroll 8
    for (int i = 0; i < 64; ++i) {
        float4 w4 = *(const float4*)(Wp + (size_t)i * E);
        float xi = xs[i];
        a.x += xi * w4.x; a.y += xi * w4.y; a.z += xi * w4.z; a.w += xi * w4.w;
    }
    atomicAdd(dst + j,     a.x);
    atomicAdd(dst + j + 1, a.y);
    atomicAdd(dst + j + 2, a.z);
    atomicAdd(dst + j + 3, a.w);
}

// Fused flash-style: per (head, 64-key chunk): copy k rows + score, local softmax,
// copy v rows + weighted accumulate. All cache traffic float4 (16B/lane).
__global__ __launch_bounds__(256) void attn_kernel(const float* __restrict__ kcache,
                                                   const float* __restrict__ vcache,
                                                   float* __restrict__ ws,
                                                   float* __restrict__ out_k,
                                                   float* __restrict__ out_v) {
    int h = blockIdx.y;
    int c = blockIdx.x;            // 0..128
    int t = threadIdx.x;
    int lane = t & 31;             // 32 lanes cover one 128-float row as float4
    int slot = t >> 5;             // 8 key-slots
    int d4 = lane * 4;

    __shared__ float sc_lds[64];
    __shared__ float sred[8];
    __shared__ float4 racc[256];

    float4 qv = *(const float4*)(ws + WS_Q + h * DH + d4);

    float sc[8];
    int base = c * 64;
#pragma unroll
    for (int i = 0; i < 8; ++i) {
        int key = base + i * 8 + slot;
        bool valid = key < L1;
        float4 kv = make_float4(0.f, 0.f, 0.f, 0.f);
        if (valid) {
            const float* src = (key < L) ? (kcache + ((size_t)key * H + h) * DH + d4)
                                         : (ws + WS_KI + h * DH + d4);
            kv = *(const float4*)src;
            *(float4*)(out_k + ((size_t)key * H + h) * DH + d4) = kv;
        }
        float d = qv.x * kv.x + qv.y * kv.y + qv.z * kv.z + qv.w * kv.w;
        d += __shfl_xor(d, 16); d += __shfl_xor(d, 8);
        d += __shfl_xor(d, 4);  d += __shfl_xor(d, 2); d += __shfl_xor(d, 1);
        sc[i] = valid ? d * 0.08838834764831845f : -INFINITY;
        if (lane == 0) sc_lds[i * 8 + slot] = sc[i];
    }
    __syncthreads();

    float m = -INFINITY;
#pragma unroll
    for (int j = 0; j < 64; ++j) m = fmaxf(m, sc_lds[j]);
    float ps = 0.f;
#pragma unroll
    for (int i = 0; i < 8; ++i) ps += __expf(sc[i] - m);   // exp(-inf)=0 for invalid
    if (lane == 0) sred[slot] = ps;
    __syncthreads();
    float s = 0.f;
#pragma unroll
    for (int j = 0; j < 8; ++j) s += sred[j];

    float4 acc = make_float4(0.f, 0.f, 0.f, 0.f);
#pragma unroll
    for (int i = 0; i < 8; ++i) {
        int key = base + i * 8 + slot;
        if (key < L1) {
            const float* src = (key < L) ? (vcache + ((size_t)key * H + h) * DH + d4)
                                         : (ws + WS_VI + h * DH + d4);
            float4 vv = *(const float4*)src;
            *(float4*)(out_v + ((size_t)key * H + h) * DH + d4) = vv;
            float w = __expf(sc[i] - m);
            acc.x += w * vv.x; acc.y += w * vv.y; acc.z += w * vv.z; acc.w += w * vv.w;
        }
    }
    racc[t] = acc;
    __syncthreads();
#pragma unroll
    for (int o = 128; o >= 32; o >>= 1) {
        if (t < o) {
            float4 b = racc[t + o];
            racc[t].x += b.x; racc[t].y += b.y; racc[t].z += b.z; racc[t].w += b.w;
        }
        __syncthreads();
    }
    float* part = ws + WS_PART + ((size_t)h * NC + c) * PSTR;
    if (t < 32) *(float4*)(part + t * 4) = racc[t];
    if (t == 0) { part[128] = m; part[129] = s; }
}

// Combine per-chunk partials: M = max m_c; S = sum s_c*exp(m_c-M); values = sum acc_c*exp(m_c-M)/S.
__global__ __launch_bounds__(128) void finalize_kernel(float* __restrict__ ws) {
    int h = blockIdx.x;
    int d = threadIdx.x;
    const float* ph = ws + WS_PART + (size_t)h * NC * PSTR;
    float M = -INFINITY;
    for (int c = 0; c < NC; ++c) M = fmaxf(M, ph[c * PSTR + 128]);
    float S = 0.f, val = 0.f;
    for (int c = 0; c < NC; ++c) {
        float e = __expf(ph[c * PSTR + 128] - M);
        S   += ph[c * PSTR + 129] * e;
        val += ph[c * PSTR + d] * e;
    }
    ws[WS_VAL + h * DH + d] = val / S;
}

// out_i = values @ Wo + bo (bias pre-seeded). float4 split-K.
__global__ __launch_bounds__(256) void outproj_kernel(const float* __restrict__ Wo,
                                                      const float* __restrict__ ws,
                                                      float* __restrict__ out) {
    int b = blockIdx.x;             // 2 jb x 32 kc
    int jb = b >> 5, kc = b & 31;
    __shared__ float xs[64];
    int t = threadIdx.x;
    if (t < 64) xs[t] = ws[WS_VAL + kc * 64 + t];
    __syncthreads();

    int j = jb * 1024 + t * 4;
    const float* Wp = Wo + (size_t)(kc * 64) * E + j;
    float4 a = make_float4(0.f, 0.f, 0.f, 0.f);
#pragma unroll 8
    for (int i = 0; i < 64; ++i) {
        float4 w4 = *(const float4*)(Wp + (size_t)i * E);
        float xi = xs[i];
        a.x += xi * w4.x; a.y += xi * w4.y; a.z += xi * w4.z; a.w += xi * w4.w;
    }
    atomicAdd(out + j,     a.x);
    atomicAdd(out + j + 1, a.y);
    atomicAdd(out + j + 2, a.z);
    atomicAdd(out + j + 3, a.w);
}

extern "C" void kernel_launch(void* const* d_in, const int* in_sizes, int n_in,
                              void* d_out, int out_size, void* d_ws, size_t ws_size,
                              hipStream_t stream) {
    const float* x  = (const float*)d_in[0];
    const float* v  = (const float*)d_in[1];
    const float* k  = (const float*)d_in[2];
    const float* Wv = (const float*)d_in[3];
    const float* bv = (const float*)d_in[4];
    const float* Wq = (const float*)d_in[5];
    const float* bq = (const float*)d_in[6];
    const float* Wk = (const float*)d_in[7];
    const float* bk = (const float*)d_in[8];
    const float* Wo = (const float*)d_in[9];
    const float* bo = (const float*)d_in[10];
    float* out = (float*)d_out;
    float* ws  = (float*)d_ws;
    float* out_v = out + E;
    float* out_k = out + E + (size_t)L1 * E;

    init_kernel<<<8, 256, 0, stream>>>(bq, bk, bv, bo, ws, out);
    proj_kernel<<<192, 256, 0, stream>>>(x, Wq, Wk, Wv, ws);
    attn_kernel<<<dim3(NC, H), 256, 0, stream>>>(k, v, ws, out_k, out_v);
    finalize_kernel<<<16, 128, 0, stream>>>(ws);
    outproj_kernel<<<64, 256, 0, stream>>>(Wo, ws, out);
}